// Round 6
// baseline (256.641 us; speedup 1.0000x reference)
//
#include <hip/hip_runtime.h>

#define M1      33                  // LPC_ORDER + 1
#define TROWS   64                  // rows per tile (= one wave, 1 row/thread)
#define BLK     64                  // single wave per block: NO barriers anywhere
#define TILE_F  (TROWS * M1)        // 2112 floats = 8448 B per tile
#define NF      8                   // full-wave float4 chunks per tile (+1 partial)
#define PARTIAL 16                  // active lanes in the partial chunk (528 = 8*64+16)
#define GRID    2304                // 9 blocks/CU * 256 CU (2*8.4 KB LDS -> 9 resident)

// Register-staged, double-buffered, barrier-free persistent pipeline.
//
// Why not global_load_lds (rounds 2/5, tied with round 0 at ~86 us): the
// compiler cannot track LDS aliasing for the DMA destination, so it inserts a
// conservative s_waitcnt vmcnt(0) before the tile's ds_reads -- draining the
// just-issued prefetch and collapsing the double-buffer to a serial
// load->wait->compute->store loop. Same net effect as __syncthreads' full
// drain in the round-0 structure: every variant so far was secretly the same
// serialized schedule (all tied 83-86 us, 2.4 TB/s, nothing saturated).
//
// Here the prefetch lands in VGPRs via plain global_load_dwordx4: the compiler
// tracks exact per-register deps and emits ONE precise counted vmcnt wait
// immediately before the staging ds_writes -- which sit AFTER the whole
// compute+store phase. Loads get a full phase of latency hiding; stores are
// never waited on.
__global__ __launch_bounds__(BLK)
void parcor_to_lpc_kernel(const float* __restrict__ k, float* __restrict__ out,
                          int ntiles) {
    __shared__ __align__(16) float lds[2 * TILE_F];   // 16.9 KB -> 9 blocks/CU
    const int lane = threadIdx.x;

    int tile = blockIdx.x;
    if (tile >= ntiles) return;
    const int stride = gridDim.x;

    float4 R[NF + 1];   // staging registers: 36 VGPR

    // ---- prologue: tile 0 global -> regs -> LDS buf 0 ----
    {
        const float4* g4 = (const float4*)(k + (size_t)tile * TILE_F);
        #pragma unroll
        for (int i = 0; i < NF; ++i) R[i] = g4[i * BLK + lane];
        if (lane < PARTIAL) R[NF] = g4[NF * BLK + lane];
        float4* l4 = (float4*)lds;
        #pragma unroll
        for (int i = 0; i < NF; ++i) l4[i * BLK + lane] = R[i];
        if (lane < PARTIAL) l4[NF * BLK + lane] = R[NF];
    }

    int buf = 0;
    while (true) {
        const int next = tile + stride;

        // ---- issue next tile's 9 loads into regs; NO wait here ----
        if (next < ntiles) {
            const float4* g4 = (const float4*)(k + (size_t)next * TILE_F);
            #pragma unroll
            for (int i = 0; i < NF; ++i) R[i] = g4[i * BLK + lane];
            if (lane < PARTIAL) R[NF] = g4[NF * BLK + lane];
        }

        float* L = lds + buf * TILE_F;

        // Staging ds_writes (prev iter, same wave) retire in order; make them
        // visible to cross-lane row reads. Single wave -> lgkm only, no barrier.
        asm volatile("s_waitcnt lgkmcnt(0)" ::: "memory");

        // ---- LDS -> regs: row stride 33 floats => bank (lane+j)%32,
        //      2-way aliasing across wave64 = conflict-free ----
        float a[M1];
        #pragma unroll
        for (int j = 0; j < M1; ++j) a[j] = L[lane * M1 + j];

        // ---- Levinson step-up recursion, fully unrolled, in registers ----
        #pragma unroll
        for (int m = 2; m < M1; ++m) {
            const float km = a[m];
            #pragma unroll
            for (int j = 1; 2 * j < m; ++j) {
                const float x = a[j];
                const float y = a[m - j];
                a[j]     = fmaf(km, y, x);
                a[m - j] = fmaf(km, x, y);
            }
            if ((m & 1) == 0) {
                const int j = m >> 1;
                a[j] = fmaf(km, a[j], a[j]);   // midpoint: a[j]*(1+km)
            }
        }

        // ---- regs -> LDS (own row), then cross-lane coalesced store ----
        #pragma unroll
        for (int j = 0; j < M1; ++j) L[lane * M1 + j] = a[j];
        asm volatile("s_waitcnt lgkmcnt(0)" ::: "memory");

        {
            const float4* l4 = (const float4*)L;
            float4* g4o = (float4*)(out + (size_t)tile * TILE_F);
            #pragma unroll
            for (int i = 0; i < NF; ++i) g4o[i * BLK + lane] = l4[i * BLK + lane];
            if (lane < PARTIAL) g4o[NF * BLK + lane] = l4[NF * BLK + lane];
        }

        if (next >= ntiles) break;

        // ---- stage next tile regs -> LDS buf^1. The compiler's precise
        //      vmcnt wait for R's loads lands HERE, a full phase after issue.
        //      Stores above were issued first (in-order vmcnt: waiting for the
        //      older loads does not require store completion). ----
        {
            float4* l4n = (float4*)(lds + (buf ^ 1) * TILE_F);
            #pragma unroll
            for (int i = 0; i < NF; ++i) l4n[i * BLK + lane] = R[i];
            if (lane < PARTIAL) l4n[NF * BLK + lane] = R[NF];
        }

        tile = next;
        buf ^= 1;
    }
}

// Fallback for trailing rows (nrows % 64 != 0) -- not hit for 16x65536.
__global__ void parcor_to_lpc_tail_kernel(const float* __restrict__ k,
                                          float* __restrict__ out,
                                          int row_start, int nrows) {
    const int row = row_start + blockIdx.x * blockDim.x + threadIdx.x;
    if (row >= nrows) return;
    const float* src = k + (size_t)row * M1;
    float* dst = out + (size_t)row * M1;
    float a[M1];
    #pragma unroll
    for (int j = 0; j < M1; ++j) a[j] = src[j];
    #pragma unroll
    for (int m = 2; m < M1; ++m) {
        const float km = a[m];
        #pragma unroll
        for (int j = 1; 2 * j < m; ++j) {
            const float x = a[j];
            const float y = a[m - j];
            a[j]     = fmaf(km, y, x);
            a[m - j] = fmaf(km, x, y);
        }
        if ((m & 1) == 0) {
            const int j = m >> 1;
            a[j] = fmaf(km, a[j], a[j]);
        }
    }
    #pragma unroll
    for (int j = 0; j < M1; ++j) dst[j] = a[j];
}

extern "C" void kernel_launch(void* const* d_in, const int* in_sizes, int n_in,
                              void* d_out, int out_size, void* d_ws, size_t ws_size,
                              hipStream_t stream) {
    const float* k = (const float*)d_in[0];
    float* out = (float*)d_out;

    const int nrows     = in_sizes[0] / M1;    // 16 * 65536 = 1,048,576
    const int ntiles    = nrows / TROWS;       // 16384 tiles
    const int tile_rows = ntiles * TROWS;
    const int rem       = nrows - tile_rows;

    if (ntiles > 0) {
        const int grid = ntiles < GRID ? ntiles : GRID;
        parcor_to_lpc_kernel<<<grid, BLK, 0, stream>>>(k, out, ntiles);
    }
    if (rem > 0)
        parcor_to_lpc_tail_kernel<<<(rem + 63) / 64, 64, 0, stream>>>(
            k, out, tile_rows, nrows);
}

// Round 7
// 242.847 us; speedup vs baseline: 1.0568x; 1.0568x over previous
//
#include <hip/hip_runtime.h>

#define M1      33                  // LPC_ORDER + 1
#define TROWS   64                  // rows per tile (= one wave, 1 row/thread)
#define BLK     64                  // single wave per block: NO barriers anywhere
#define TILE_F  (TROWS * M1)        // 2112 floats = 8448 B per tile
#define PARTIAL 16                  // active lanes in the partial chunk (528 = 8*64+16)
#define GRID    2304                // 9 blocks/CU * 256 CU (2*8.4 KB LDS -> 9 resident)

// Register-staged, double-buffered, barrier-free persistent pipeline.
//
// Round-6 post-mortem: identical structure at default launch bounds spilled
// the 36-VGPR staging block to scratch (VGPR_Count=68 < ~80 live;
// WRITE_SIZE exactly doubled 135->269 MB = 16384 tiles x 64 lanes x 32 regs
// x 4 B round-trip). The spill both added 190 MB of HBM traffic and
// re-serialized the pipeline (scratch-store of R forces the vmcnt wait at
// issue). Yet hbm_gbps hit 4.0 TB/s -- proof the 2.4 TB/s plateau of rounds
// 0-5 was never a hardware ceiling, just serialization.
//
// Fix: __launch_bounds__(64,1) -> VGPR cap 512 (occupancy is LDS-bound at 9
// single-wave blocks/CU regardless), and 9 individually-named float4 staging
// registers so SROA cannot fail. Verification signal: VGPR_Count ~100-115,
// WRITE_SIZE back to 135 MB.
__global__ __launch_bounds__(BLK, 1)
void parcor_to_lpc_kernel(const float* __restrict__ k, float* __restrict__ out,
                          int ntiles) {
    __shared__ __align__(16) float lds[2 * TILE_F];   // 16.9 KB -> 9 blocks/CU
    const int lane = threadIdx.x;

    int tile = blockIdx.x;
    if (tile >= ntiles) return;
    const int stride = gridDim.x;

    float4 R0, R1, R2, R3, R4, R5, R6, R7, R8;   // 36 VGPR staging block

#define LOAD_TILE(gbase)  do {                                        \
        const float4* g4_ = (const float4*)(gbase);                   \
        R0 = g4_[0 * BLK + lane];  R1 = g4_[1 * BLK + lane];          \
        R2 = g4_[2 * BLK + lane];  R3 = g4_[3 * BLK + lane];          \
        R4 = g4_[4 * BLK + lane];  R5 = g4_[5 * BLK + lane];          \
        R6 = g4_[6 * BLK + lane];  R7 = g4_[7 * BLK + lane];          \
        if (lane < PARTIAL) R8 = g4_[8 * BLK + lane];                 \
    } while (0)

#define STAGE_TILE(lbase) do {                                        \
        float4* l4_ = (float4*)(lbase);                               \
        l4_[0 * BLK + lane] = R0;  l4_[1 * BLK + lane] = R1;          \
        l4_[2 * BLK + lane] = R2;  l4_[3 * BLK + lane] = R3;          \
        l4_[4 * BLK + lane] = R4;  l4_[5 * BLK + lane] = R5;          \
        l4_[6 * BLK + lane] = R6;  l4_[7 * BLK + lane] = R7;          \
        if (lane < PARTIAL) l4_[8 * BLK + lane] = R8;                 \
    } while (0)

    // ---- prologue: tile 0 global -> regs -> LDS buf 0 ----
    LOAD_TILE(k + (size_t)tile * TILE_F);
    STAGE_TILE(lds);

    int buf = 0;
    while (true) {
        const int next = tile + stride;

        // ---- issue next tile's 9 loads into regs; NO wait here ----
        if (next < ntiles)
            LOAD_TILE(k + (size_t)next * TILE_F);

        float* L = lds + buf * TILE_F;

        // Staging ds_writes (prev iter, same wave) retire in order; make them
        // visible to cross-lane row reads. Single wave -> lgkm only, no barrier.
        asm volatile("s_waitcnt lgkmcnt(0)" ::: "memory");

        // ---- LDS -> regs: row stride 33 floats => bank (lane+j)%32,
        //      2-way aliasing across wave64 = conflict-free ----
        float a[M1];
        #pragma unroll
        for (int j = 0; j < M1; ++j) a[j] = L[lane * M1 + j];

        // ---- Levinson step-up recursion, fully unrolled, in registers ----
        #pragma unroll
        for (int m = 2; m < M1; ++m) {
            const float km = a[m];
            #pragma unroll
            for (int j = 1; 2 * j < m; ++j) {
                const float x = a[j];
                const float y = a[m - j];
                a[j]     = fmaf(km, y, x);
                a[m - j] = fmaf(km, x, y);
            }
            if ((m & 1) == 0) {
                const int j = m >> 1;
                a[j] = fmaf(km, a[j], a[j]);   // midpoint: a[j]*(1+km)
            }
        }

        // ---- regs -> LDS (own row), then cross-lane coalesced store ----
        #pragma unroll
        for (int j = 0; j < M1; ++j) L[lane * M1 + j] = a[j];
        asm volatile("s_waitcnt lgkmcnt(0)" ::: "memory");

        {
            const float4* l4 = (const float4*)L;
            float4* g4o = (float4*)(out + (size_t)tile * TILE_F);
            #pragma unroll
            for (int i = 0; i < 8; ++i) g4o[i * BLK + lane] = l4[i * BLK + lane];
            if (lane < PARTIAL) g4o[8 * BLK + lane] = l4[8 * BLK + lane];
        }

        if (next >= ntiles) break;

        // ---- stage next tile regs -> LDS buf^1. The compiler's precise
        //      counted vmcnt wait for the R loads lands HERE, a full
        //      compute+store phase after issue. ----
        STAGE_TILE(lds + (buf ^ 1) * TILE_F);

        tile = next;
        buf ^= 1;
    }
#undef LOAD_TILE
#undef STAGE_TILE
}

// Fallback for trailing rows (nrows % 64 != 0) -- not hit for 16x65536.
__global__ void parcor_to_lpc_tail_kernel(const float* __restrict__ k,
                                          float* __restrict__ out,
                                          int row_start, int nrows) {
    const int row = row_start + blockIdx.x * blockDim.x + threadIdx.x;
    if (row >= nrows) return;
    const float* src = k + (size_t)row * M1;
    float* dst = out + (size_t)row * M1;
    float a[M1];
    #pragma unroll
    for (int j = 0; j < M1; ++j) a[j] = src[j];
    #pragma unroll
    for (int m = 2; m < M1; ++m) {
        const float km = a[m];
        #pragma unroll
        for (int j = 1; 2 * j < m; ++j) {
            const float x = a[j];
            const float y = a[m - j];
            a[j]     = fmaf(km, y, x);
            a[m - j] = fmaf(km, x, y);
        }
        if ((m & 1) == 0) {
            const int j = m >> 1;
            a[j] = fmaf(km, a[j], a[j]);
        }
    }
    #pragma unroll
    for (int j = 0; j < M1; ++j) dst[j] = a[j];
}

extern "C" void kernel_launch(void* const* d_in, const int* in_sizes, int n_in,
                              void* d_out, int out_size, void* d_ws, size_t ws_size,
                              hipStream_t stream) {
    const float* k = (const float*)d_in[0];
    float* out = (float*)d_out;

    const int nrows     = in_sizes[0] / M1;    // 16 * 65536 = 1,048,576
    const int ntiles    = nrows / TROWS;       // 16384 tiles
    const int tile_rows = ntiles * TROWS;
    const int rem       = nrows - tile_rows;

    if (ntiles > 0) {
        const int grid = ntiles < GRID ? ntiles : GRID;
        parcor_to_lpc_kernel<<<grid, BLK, 0, stream>>>(k, out, ntiles);
    }
    if (rem > 0)
        parcor_to_lpc_tail_kernel<<<(rem + 63) / 64, 64, 0, stream>>>(
            k, out, tile_rows, nrows);
}

// Round 9
// 241.228 us; speedup vs baseline: 1.0639x; 1.0067x over previous
//
#include <hip/hip_runtime.h>

#define M1      33                  // LPC_ORDER + 1
#define TROWS   64                  // rows per tile (= one wave, 1 row/thread)
#define BLK     64                  // single wave per block: NO barriers anywhere
#define TILE_F  (TROWS * M1)        // 2112 floats = 8448 B per tile
#define PARTIAL 16                  // active lanes in the partial chunk (528 = 8*64+16)
#define BPC     18                  // resident blocks/CU: LDS 8448 B -> 19 max, 18 safe
#define GRID    (BPC * 256)         // 4608 persistent blocks

// Depth-2 register-prefetch, SINGLE-buffer LDS, barrier-free persistent loop.
//
// Ledger: five schedules (4-phase barrier, global_load_lds dbuf, nt-stores,
// reg-staged dbuf) all tied at 83-93 us / ~2.4 TB/s with every pipe <20%.
// Round 6's spill variant moved 397 MB in ~100 us (4.0 TB/s) -- duration
// flat while bytes doubled -> NOT bandwidth-bound at 2.4. fillBufferAligned
// does 6.7 TB/s at 9.75% occupancy because stores are fire-and-forget: its
// waves keep dozens of VMEM ops outstanding. Our waves held <=9 reads in
// flight, briefly. Gate = per-wave outstanding reads x waves (Little's law).
//
// This version: (a) single LDS buffer (reg staging makes dbuf unnecessary:
// next tile's ds_writes follow all prior reads in program order) -> 18
// blocks/CU instead of 9; (b) two named register sets A/B, 2-unrolled loop:
// set B's 9 loads stay in flight across set A's entire compute+store and
// vice versa -> 9-18 reads outstanding per wave at ALL times. Compiler's
// precise per-register vmcnt waits land one full iteration after issue.
__global__ __launch_bounds__(BLK, 1)
void parcor_to_lpc_kernel(const float* __restrict__ k, float* __restrict__ out,
                          int ntiles) {
    __shared__ __align__(16) float lds[TILE_F];   // 8448 B single buffer
    const int lane = threadIdx.x;

    int tA = blockIdx.x;
    if (tA >= ntiles) return;
    const int stride  = gridDim.x;
    const int stride2 = 2 * stride;

    float4 A0, A1, A2, A3, A4, A5, A6, A7, A8;    // prefetch set A (36 VGPR)
    float4 B0, B1, B2, B3, B4, B5, B6, B7, B8;    // prefetch set B (36 VGPR)

#define LOADSET(P, gbase) do {                                          \
        const float4* g4_ = (const float4*)(gbase);                     \
        P##0 = g4_[0 * BLK + lane];  P##1 = g4_[1 * BLK + lane];        \
        P##2 = g4_[2 * BLK + lane];  P##3 = g4_[3 * BLK + lane];        \
        P##4 = g4_[4 * BLK + lane];  P##5 = g4_[5 * BLK + lane];        \
        P##6 = g4_[6 * BLK + lane];  P##7 = g4_[7 * BLK + lane];        \
        if (lane < PARTIAL) P##8 = g4_[8 * BLK + lane];                 \
    } while (0)

#define STAGESET(P) do {                                                \
        float4* l4_ = (float4*)lds;                                     \
        l4_[0 * BLK + lane] = P##0;  l4_[1 * BLK + lane] = P##1;        \
        l4_[2 * BLK + lane] = P##2;  l4_[3 * BLK + lane] = P##3;        \
        l4_[4 * BLK + lane] = P##4;  l4_[5 * BLK + lane] = P##5;        \
        l4_[6 * BLK + lane] = P##6;  l4_[7 * BLK + lane] = P##7;        \
        if (lane < PARTIAL) l4_[8 * BLK + lane] = P##8;                 \
    } while (0)

    // Compute tile from LDS and store it. Cross-lane visibility points use
    // lgkmcnt(0) only (single wave, no barrier => no vmcnt drain). The
    // store-phase ds_reads retire before the next STAGESET's ds_writes
    // (same-wave DS ops execute in order; compiler also waits lgkm for the
    // store data), so single-buffer reuse is safe.
#define PROCESS(tidx) do {                                              \
        asm volatile("s_waitcnt lgkmcnt(0)" ::: "memory");              \
        float a[M1];                                                    \
        _Pragma("unroll")                                               \
        for (int j = 0; j < M1; ++j) a[j] = lds[lane * M1 + j];         \
        _Pragma("unroll")                                               \
        for (int m = 2; m < M1; ++m) {                                  \
            const float km = a[m];                                      \
            _Pragma("unroll")                                           \
            for (int j = 1; 2 * j < m; ++j) {                           \
                const float x = a[j];                                   \
                const float y = a[m - j];                               \
                a[j]     = fmaf(km, y, x);                              \
                a[m - j] = fmaf(km, x, y);                              \
            }                                                           \
            if ((m & 1) == 0) {                                         \
                const int j_ = m >> 1;                                  \
                a[j_] = fmaf(km, a[j_], a[j_]);                         \
            }                                                           \
        }                                                               \
        _Pragma("unroll")                                               \
        for (int j = 0; j < M1; ++j) lds[lane * M1 + j] = a[j];         \
        asm volatile("s_waitcnt lgkmcnt(0)" ::: "memory");              \
        const float4* l4_ = (const float4*)lds;                         \
        float4* g4o_ = (float4*)(out + (size_t)(tidx) * TILE_F);        \
        _Pragma("unroll")                                               \
        for (int i = 0; i < 8; ++i)                                     \
            g4o_[i * BLK + lane] = l4_[i * BLK + lane];                 \
        if (lane < PARTIAL) g4o_[8 * BLK + lane] = l4_[8 * BLK + lane]; \
    } while (0)

    // ---- prologue: fill the 2-deep pipeline ----
    LOADSET(A, k + (size_t)tA * TILE_F);
    int tB = tA + stride;
    if (tB < ntiles)
        LOADSET(B, k + (size_t)tB * TILE_F);

    while (true) {
        // ---- half 1: tile tA from set A; refill A <- tA+2*stride ----
        STAGESET(A);                       // compiler vmcnt wait: A's loads (1 iter old)
        {
            const int tN = tA + stride2;   // uniform branch, no divergence
            if (tN < ntiles) LOADSET(A, k + (size_t)tN * TILE_F);
        }
        PROCESS(tA);
        if (tB >= ntiles) break;
        tA += stride2;

        // ---- half 2: tile tB from set B; refill B <- tB+2*stride ----
        STAGESET(B);
        {
            const int tN = tB + stride2;
            if (tN < ntiles) LOADSET(B, k + (size_t)tN * TILE_F);
        }
        PROCESS(tB);
        if (tA >= ntiles) break;
        tB += stride2;
    }

#undef LOADSET
#undef STAGESET
#undef PROCESS
}

// Fallback for trailing rows (nrows % 64 != 0) -- not hit for 16x65536.
__global__ void parcor_to_lpc_tail_kernel(const float* __restrict__ k,
                                          float* __restrict__ out,
                                          int row_start, int nrows) {
    const int row = row_start + blockIdx.x * blockDim.x + threadIdx.x;
    if (row >= nrows) return;
    const float* src = k + (size_t)row * M1;
    float* dst = out + (size_t)row * M1;
    float a[M1];
    #pragma unroll
    for (int j = 0; j < M1; ++j) a[j] = src[j];
    #pragma unroll
    for (int m = 2; m < M1; ++m) {
        const float km = a[m];
        #pragma unroll
        for (int j = 1; 2 * j < m; ++j) {
            const float x = a[j];
            const float y = a[m - j];
            a[j]     = fmaf(km, y, x);
            a[m - j] = fmaf(km, x, y);
        }
        if ((m & 1) == 0) {
            const int j = m >> 1;
            a[j] = fmaf(km, a[j], a[j]);
        }
    }
    #pragma unroll
    for (int j = 0; j < M1; ++j) dst[j] = a[j];
}

extern "C" void kernel_launch(void* const* d_in, const int* in_sizes, int n_in,
                              void* d_out, int out_size, void* d_ws, size_t ws_size,
                              hipStream_t stream) {
    const float* k = (const float*)d_in[0];
    float* out = (float*)d_out;

    const int nrows     = in_sizes[0] / M1;    // 16 * 65536 = 1,048,576
    const int ntiles    = nrows / TROWS;       // 16384 tiles
    const int tile_rows = ntiles * TROWS;
    const int rem       = nrows - tile_rows;

    if (ntiles > 0) {
        const int grid = ntiles < GRID ? ntiles : GRID;
        parcor_to_lpc_kernel<<<grid, BLK, 0, stream>>>(k, out, ntiles);
    }
    if (rem > 0)
        parcor_to_lpc_tail_kernel<<<(rem + 63) / 64, 64, 0, stream>>>(
            k, out, tile_rows, nrows);
}